// Round 6
// baseline (227.472 us; speedup 1.0000x reference)
//
#include <hip/hip_runtime.h>

// ImplicitNetOC: u = clip(-pB) ; pB = relu(relu([x,t]W1+b1)W2+b2) @ (W3@Bmat) + b3@Bmat
// R6: BM=64 / 76.8 KB LDS -> 2 blocks/CU (16 waves/CU) to hide the 4 barriers/tile
// that bounded R5 at 1 block/CU. W3B frags live in d_ws (not VGPRs); biases fold
// into acc init; waves 4-7 stage next X while waves 0-3 run layer 3.

typedef __bf16 bf16;
typedef __bf16 bf16x8 __attribute__((ext_vector_type(8)));
typedef __bf16 bf16x4 __attribute__((ext_vector_type(4)));
typedef float  f32x4  __attribute__((ext_vector_type(4)));

#define HID    256
#define SDIM   64
#define CDIM   16
#define BM     64
#define GRID   512      // 2 blocks per CU
#define ITERS  4        // 131072 / (BM*GRID)
#define LDH    264      // bf16 stride (528 B = 132 dw == 4 mod 32 banks: balanced)
#define LDX    72       // bf16 stride (144 B = 36 dw == 4 mod 32 banks: balanced)

#define MFMA(a, b, c) __builtin_amdgcn_mfma_f32_16x16x32_bf16(a, b, c, 0, 0, 0)

__device__ __forceinline__ int sh_idx(int row, int h) { return row * LDH + h; }

__global__ __launch_bounds__(512, 4)
void oc_main(const float* __restrict__ x,  const float* __restrict__ t,
             const float* __restrict__ W1, const float* __restrict__ b1,
             const float* __restrict__ W2, const float* __restrict__ b2,
             const float* __restrict__ W3, const float* __restrict__ b3,
             const float* __restrict__ Bmat, bf16* __restrict__ w3ws,
             float* __restrict__ out) {
  __shared__ bf16 sH1[BM * LDH];   // H1 [batch][hidden]; reused as H2-lo
  __shared__ bf16 sH2[BM * LDH];   // H2-hi
  __shared__ bf16 sX [BM * LDX];   // staged X [batch][k]
  const int tid  = threadIdx.x;
  const int wave = tid >> 6, lane = tid & 63;
  const int q    = lane >> 4, l = lane & 15;

  // ---- phase 0: W3B^T A-frags -> ws (each block writes identical data; it reads
  //      only its own writes -> same-CU/L2 path, no cross-XCD hazard). thread = (kt,lane):
  //      frag elems jj=0..7 are hidden rows r0..r0+7, control col = lane&15.
  {
    const int kt = tid >> 6, fl = tid & 63;
    const int r0 = kt * 32 + ((fl >> 4) << 3);
    const int c  = fl & 15;
    float aw[8];
#pragma unroll
    for (int j = 0; j < 8; ++j) aw[j] = 0.f;
    for (int m = 0; m < SDIM; ++m) {
      const float bm = Bmat[m * CDIM + c];
#pragma unroll
      for (int j = 0; j < 8; ++j) aw[j] = fmaf(W3[(r0 + j) * SDIM + m], bm, aw[j]);
    }
    bf16x8 v;
#pragma unroll
    for (int j = 0; j < 8; ++j) v[j] = (bf16)aw[j];
    *(bf16x8*)(w3ws + (size_t)tid * 8) = v;
  }

  // ---- initial X stage: all 512 threads, 2 float4 each ----
  {
    const float* xp = x + (size_t)blockIdx.x * BM * SDIM;
#pragma unroll
    for (int i = 0; i < 2; ++i) {
      const int e = i * 512 + tid;           // 1024 float4 = 64 x 64 floats
      const int r = e >> 4, k4 = (e & 15) * 4;
      const float4 v = *(const float4*)(xp + r * SDIM + k4);
      bf16x4 w = {(bf16)v.x, (bf16)v.y, (bf16)v.z, (bf16)v.w};
      *(bf16x4*)(&sX[r * LDX + k4]) = w;
    }
  }

  // ---- weight A-frags (register-resident) + biases ----
  bf16x8 W1t[2][2], W2t[8][2];
#pragma unroll
  for (int kt = 0; kt < 2; ++kt)
#pragma unroll
    for (int mt = 0; mt < 2; ++mt) {
      bf16x8 v;
#pragma unroll
      for (int j = 0; j < 8; ++j)
        v[j] = (bf16)W1[(32 * kt + 8 * q + j) * HID + 32 * wave + 16 * mt + l];
      W1t[kt][mt] = v;
    }
#pragma unroll
  for (int kt = 0; kt < 8; ++kt)
#pragma unroll
    for (int mt = 0; mt < 2; ++mt) {
      bf16x8 v;
#pragma unroll
      for (int j = 0; j < 8; ++j)
        v[j] = (bf16)W2[(32 * kt + 8 * q + j) * HID + 32 * wave + 16 * mt + l];
      W2t[kt][mt] = v;
    }

  const float tt = t[0];
  f32x4 b1e[2], b2e[2];
#pragma unroll
  for (int mt = 0; mt < 2; ++mt)
#pragma unroll
    for (int r = 0; r < 4; ++r) {
      const int h = 32 * wave + 16 * mt + 4 * q + r;
      b1e[mt][r] = b1[h] + tt * W1[SDIM * HID + h];   // fold t-column of zt
      b2e[mt][r] = b2[h];
    }
  f32x4 b3t;
#pragma unroll
  for (int r = 0; r < 4; ++r) b3t[r] = 0.f;
  for (int m = 0; m < SDIM; ++m) {
    const float bm = b3[m];
    const float4 v = *(const float4*)(&Bmat[m * CDIM + 4 * q]);
    b3t[0] = fmaf(bm, v.x, b3t[0]); b3t[1] = fmaf(bm, v.y, b3t[1]);
    b3t[2] = fmaf(bm, v.z, b3t[2]); b3t[3] = fmaf(bm, v.w, b3t[3]);
  }
  __syncthreads();   // sX staged; w3ws visible block-wide (syncthreads fences global)

  f32x4 acc[2][4];

  for (int it = 0; it < ITERS; ++it) {
    const int tile = blockIdx.x + it * GRID;

    // ---- layer 1: H1 = relu(W1^T X^T + b1)  M=32 hidden/wave, N=64 batch ----
#pragma unroll
    for (int mt = 0; mt < 2; ++mt)
#pragma unroll
      for (int nt = 0; nt < 4; ++nt) acc[mt][nt] = b1e[mt];
#pragma unroll
    for (int kt = 0; kt < 2; ++kt)
#pragma unroll
      for (int nt = 0; nt < 4; ++nt) {
        const bf16x8 b = *(const bf16x8*)(&sX[(16 * nt + l) * LDX + 32 * kt + 8 * q]);
        acc[0][nt] = MFMA(W1t[kt][0], b, acc[0][nt]);
        acc[1][nt] = MFMA(W1t[kt][1], b, acc[1][nt]);
      }
#pragma unroll
    for (int mt = 0; mt < 2; ++mt) {
      const int h0 = 32 * wave + 16 * mt + 4 * q;
#pragma unroll
      for (int nt = 0; nt < 4; ++nt) {
        bf16x4 v;
#pragma unroll
        for (int r = 0; r < 4; ++r) v[r] = (bf16)fmaxf(acc[mt][nt][r], 0.f);
        *(bf16x4*)(&sH1[sh_idx(16 * nt + l, h0)]) = v;
      }
    }
    __syncthreads();   // A: H1 visible; sX reads done

    // ---- layer 2: H2 = relu(W2^T H1 + b2)  K=256 ----
#pragma unroll
    for (int mt = 0; mt < 2; ++mt)
#pragma unroll
      for (int nt = 0; nt < 4; ++nt) acc[mt][nt] = b2e[mt];
#pragma unroll
    for (int kt = 0; kt < 8; ++kt)
#pragma unroll
      for (int nt = 0; nt < 4; ++nt) {
        const bf16x8 b = *(const bf16x8*)(&sH1[sh_idx(16 * nt + l, 32 * kt + 8 * q)]);
        acc[0][nt] = MFMA(W2t[kt][0], b, acc[0][nt]);
        acc[1][nt] = MFMA(W2t[kt][1], b, acc[1][nt]);
      }
    __syncthreads();   // B: sH1 reads done -> overwritable as H2-lo

    // ---- H2 writeback: hi (sH2) + lo residual (sH1), b64 each ----
#pragma unroll
    for (int mt = 0; mt < 2; ++mt) {
      const int h0 = 32 * wave + 16 * mt + 4 * q;
#pragma unroll
      for (int nt = 0; nt < 4; ++nt) {
        bf16x4 hi, lo;
#pragma unroll
        for (int r = 0; r < 4; ++r) {
          const float v = fmaxf(acc[mt][nt][r], 0.f);
          const bf16 h = (bf16)v;
          hi[r] = h;
          lo[r] = (bf16)(v - (float)h);
        }
        const int idx = sh_idx(16 * nt + l, h0);
        *(bf16x4*)(&sH2[idx]) = hi;
        *(bf16x4*)(&sH1[idx]) = lo;
      }
    }
    __syncthreads();   // C: H2 hi/lo visible

    if (wave < 4) {
      // ---- layer 3 (waves 0-3): u = clip(-(W3B^T(H2hi+H2lo) + b3B)), 16 rows/wave ----
      f32x4 a3 = b3t;
#pragma unroll
      for (int kt = 0; kt < 8; ++kt) {
        const bf16x8 w3 = *(const bf16x8*)(w3ws + ((size_t)kt * 64 + lane) * 8);
        const int idx = sh_idx(16 * wave + l, 32 * kt + 8 * q);
        const bf16x8 bh = *(const bf16x8*)(&sH2[idx]);
        const bf16x8 bl = *(const bf16x8*)(&sH1[idx]);
        a3 = MFMA(w3, bh, a3);
        a3 = MFMA(w3, bl, a3);
      }
      f32x4 o;
#pragma unroll
      for (int r = 0; r < 4; ++r)
        o[r] = fminf(fmaxf(-a3[r], -1.f), 1.f);
      *(float4*)(&out[((size_t)tile * BM + 16 * wave + l) * CDIM + 4 * q]) = *(float4*)&o;
    } else if (it + 1 < ITERS) {
      // ---- waves 4-7: stage next X tile concurrently with layer 3 ----
      const float* xp = x + (size_t)(tile + GRID) * BM * SDIM;
      const int tid2 = tid - 256;
#pragma unroll
      for (int i = 0; i < 4; ++i) {
        const int e = i * 256 + tid2;        // 1024 float4 = 64 x 64 floats
        const int r = e >> 4, k4 = (e & 15) * 4;
        const float4 v = *(const float4*)(xp + r * SDIM + k4);
        bf16x4 w = {(bf16)v.x, (bf16)v.y, (bf16)v.z, (bf16)v.w};
        *(bf16x4*)(&sX[r * LDX + k4]) = w;
      }
    }
    __syncthreads();   // D: L3 reads + stage done before next L1 overwrites sH1/reads sX
  }
}

extern "C" void kernel_launch(void* const* d_in, const int* in_sizes, int n_in,
                              void* d_out, int out_size, void* d_ws, size_t ws_size,
                              hipStream_t stream) {
  const float* x    = (const float*)d_in[0];
  const float* t    = (const float*)d_in[1];
  const float* W1   = (const float*)d_in[2];
  const float* b1   = (const float*)d_in[3];
  const float* W2   = (const float*)d_in[4];
  const float* b2   = (const float*)d_in[5];
  const float* W3   = (const float*)d_in[6];
  const float* b3   = (const float*)d_in[7];
  const float* Bmat = (const float*)d_in[8];
  float* out = (float*)d_out;
  bf16*  w3ws = (bf16*)d_ws;

  hipLaunchKernelGGL(oc_main, dim3(GRID), dim3(512), 0, stream,
                     x, t, W1, b1, W2, b2, W3, b3, Bmat, w3ws, out);
}

// Round 7
// 220.908 us; speedup vs baseline: 1.0297x; 1.0297x over previous
//
#include <hip/hip_runtime.h>

// ImplicitNetOC: u = clip(-pB) ; pB = relu(relu([x,t]W1+b1)W2+b2) @ (W3@Bmat) + b3@Bmat
// R7 = R6 (BM=64, 2 blocks/CU, W3B frags in d_ws, bias-in-acc, stage/L3 wave split)
// with the register allocator PINNED at 4 waves/EU (VGPR budget 128). R6's
// __launch_bounds__(512,4) set only a MINIMUM; the compiler chased 8 waves/EU with
// 64 VGPRs and spilled the weight fragments to scratch (166 MB of spill writes).

typedef __bf16 bf16;
typedef __bf16 bf16x8 __attribute__((ext_vector_type(8)));
typedef __bf16 bf16x4 __attribute__((ext_vector_type(4)));
typedef float  f32x4  __attribute__((ext_vector_type(4)));

#define HID    256
#define SDIM   64
#define CDIM   16
#define BM     64
#define GRID   512      // 2 blocks per CU
#define ITERS  4        // 131072 / (BM*GRID)
#define LDH    264      // bf16 stride (528 B = 132 dw == 4 mod 32 banks: balanced)
#define LDX    72       // bf16 stride (144 B = 36 dw == 4 mod 32 banks: balanced)

#define MFMA(a, b, c) __builtin_amdgcn_mfma_f32_16x16x32_bf16(a, b, c, 0, 0, 0)

__device__ __forceinline__ int sh_idx(int row, int h) { return row * LDH + h; }

__global__
__attribute__((amdgpu_flat_work_group_size(512, 512), amdgpu_waves_per_eu(4, 4)))
void oc_main(const float* __restrict__ x,  const float* __restrict__ t,
             const float* __restrict__ W1, const float* __restrict__ b1,
             const float* __restrict__ W2, const float* __restrict__ b2,
             const float* __restrict__ W3, const float* __restrict__ b3,
             const float* __restrict__ Bmat, bf16* __restrict__ w3ws,
             float* __restrict__ out) {
  __shared__ bf16 sH1[BM * LDH];   // H1 [batch][hidden]; reused as H2-lo
  __shared__ bf16 sH2[BM * LDH];   // H2-hi
  __shared__ bf16 sX [BM * LDX];   // staged X [batch][k]
  const int tid  = threadIdx.x;
  const int wave = tid >> 6, lane = tid & 63;
  const int q    = lane >> 4, l = lane & 15;

  // ---- phase 0: W3B^T A-frags -> ws (each block writes identical data and reads
  //      only its own writes; same-CU L2 path, no cross-XCD hazard). thread = (kt,lane).
  {
    const int kt = tid >> 6, fl = tid & 63;
    const int r0 = kt * 32 + ((fl >> 4) << 3);
    const int c  = fl & 15;
    float aw[8];
#pragma unroll
    for (int j = 0; j < 8; ++j) aw[j] = 0.f;
    for (int m = 0; m < SDIM; ++m) {
      const float bm = Bmat[m * CDIM + c];
#pragma unroll
      for (int j = 0; j < 8; ++j) aw[j] = fmaf(W3[(r0 + j) * SDIM + m], bm, aw[j]);
    }
    bf16x8 v;
#pragma unroll
    for (int j = 0; j < 8; ++j) v[j] = (bf16)aw[j];
    *(bf16x8*)(w3ws + (size_t)tid * 8) = v;
  }

  // ---- initial X stage: all 512 threads, 2 float4 each ----
  {
    const float* xp = x + (size_t)blockIdx.x * BM * SDIM;
#pragma unroll
    for (int i = 0; i < 2; ++i) {
      const int e = i * 512 + tid;           // 1024 float4 = 64 x 64 floats
      const int r = e >> 4, k4 = (e & 15) * 4;
      const float4 v = *(const float4*)(xp + r * SDIM + k4);
      bf16x4 w = {(bf16)v.x, (bf16)v.y, (bf16)v.z, (bf16)v.w};
      *(bf16x4*)(&sX[r * LDX + k4]) = w;
    }
  }

  // ---- weight A-frags (register-resident) + biases ----
  bf16x8 W1t[2][2], W2t[8][2];
#pragma unroll
  for (int kt = 0; kt < 2; ++kt)
#pragma unroll
    for (int mt = 0; mt < 2; ++mt) {
      bf16x8 v;
#pragma unroll
      for (int j = 0; j < 8; ++j)
        v[j] = (bf16)W1[(32 * kt + 8 * q + j) * HID + 32 * wave + 16 * mt + l];
      W1t[kt][mt] = v;
    }
#pragma unroll
  for (int kt = 0; kt < 8; ++kt)
#pragma unroll
    for (int mt = 0; mt < 2; ++mt) {
      bf16x8 v;
#pragma unroll
      for (int j = 0; j < 8; ++j)
        v[j] = (bf16)W2[(32 * kt + 8 * q + j) * HID + 32 * wave + 16 * mt + l];
      W2t[kt][mt] = v;
    }

  const float tt = t[0];
  f32x4 b1e[2], b2e[2];
#pragma unroll
  for (int mt = 0; mt < 2; ++mt)
#pragma unroll
    for (int r = 0; r < 4; ++r) {
      const int h = 32 * wave + 16 * mt + 4 * q + r;
      b1e[mt][r] = b1[h] + tt * W1[SDIM * HID + h];   // fold t-column of zt
      b2e[mt][r] = b2[h];
    }
  f32x4 b3t;
#pragma unroll
  for (int r = 0; r < 4; ++r) b3t[r] = 0.f;
  for (int m = 0; m < SDIM; ++m) {
    const float bm = b3[m];
    const float4 v = *(const float4*)(&Bmat[m * CDIM + 4 * q]);
    b3t[0] = fmaf(bm, v.x, b3t[0]); b3t[1] = fmaf(bm, v.y, b3t[1]);
    b3t[2] = fmaf(bm, v.z, b3t[2]); b3t[3] = fmaf(bm, v.w, b3t[3]);
  }
  __syncthreads();   // sX staged; w3ws drained (waitcnt before barrier)

  f32x4 acc[2][4];

  for (int it = 0; it < ITERS; ++it) {
    const int tile = blockIdx.x + it * GRID;

    // ---- layer 1: H1 = relu(W1^T X^T + b1)  M=32 hidden/wave, N=64 batch ----
#pragma unroll
    for (int mt = 0; mt < 2; ++mt)
#pragma unroll
      for (int nt = 0; nt < 4; ++nt) acc[mt][nt] = b1e[mt];
#pragma unroll
    for (int kt = 0; kt < 2; ++kt)
#pragma unroll
      for (int nt = 0; nt < 4; ++nt) {
        const bf16x8 b = *(const bf16x8*)(&sX[(16 * nt + l) * LDX + 32 * kt + 8 * q]);
        acc[0][nt] = MFMA(W1t[kt][0], b, acc[0][nt]);
        acc[1][nt] = MFMA(W1t[kt][1], b, acc[1][nt]);
      }
#pragma unroll
    for (int mt = 0; mt < 2; ++mt) {
      const int h0 = 32 * wave + 16 * mt + 4 * q;
#pragma unroll
      for (int nt = 0; nt < 4; ++nt) {
        bf16x4 v;
#pragma unroll
        for (int r = 0; r < 4; ++r) v[r] = (bf16)fmaxf(acc[mt][nt][r], 0.f);
        *(bf16x4*)(&sH1[sh_idx(16 * nt + l, h0)]) = v;
      }
    }
    __syncthreads();   // A: H1 visible; sX reads done

    // ---- layer 2: H2 = relu(W2^T H1 + b2)  K=256 ----
#pragma unroll
    for (int mt = 0; mt < 2; ++mt)
#pragma unroll
      for (int nt = 0; nt < 4; ++nt) acc[mt][nt] = b2e[mt];
#pragma unroll
    for (int kt = 0; kt < 8; ++kt)
#pragma unroll
      for (int nt = 0; nt < 4; ++nt) {
        const bf16x8 b = *(const bf16x8*)(&sH1[sh_idx(16 * nt + l, 32 * kt + 8 * q)]);
        acc[0][nt] = MFMA(W2t[kt][0], b, acc[0][nt]);
        acc[1][nt] = MFMA(W2t[kt][1], b, acc[1][nt]);
      }
    __syncthreads();   // B: sH1 reads done -> overwritable as H2-lo

    // ---- H2 writeback: hi (sH2) + lo residual (sH1), b64 each ----
#pragma unroll
    for (int mt = 0; mt < 2; ++mt) {
      const int h0 = 32 * wave + 16 * mt + 4 * q;
#pragma unroll
      for (int nt = 0; nt < 4; ++nt) {
        bf16x4 hi, lo;
#pragma unroll
        for (int r = 0; r < 4; ++r) {
          const float v = fmaxf(acc[mt][nt][r], 0.f);
          const bf16 h = (bf16)v;
          hi[r] = h;
          lo[r] = (bf16)(v - (float)h);
        }
        const int idx = sh_idx(16 * nt + l, h0);
        *(bf16x4*)(&sH2[idx]) = hi;
        *(bf16x4*)(&sH1[idx]) = lo;
      }
    }
    __syncthreads();   // C: H2 hi/lo visible

    if (wave < 4) {
      // ---- layer 3 (waves 0-3): u = clip(-(W3B^T(H2hi+H2lo) + b3B)), 16 rows/wave ----
      f32x4 a3 = b3t;
#pragma unroll
      for (int kt = 0; kt < 8; ++kt) {
        const bf16x8 w3 = *(const bf16x8*)(w3ws + ((size_t)kt * 64 + lane) * 8);
        const int idx = sh_idx(16 * wave + l, 32 * kt + 8 * q);
        const bf16x8 bh = *(const bf16x8*)(&sH2[idx]);
        const bf16x8 bl = *(const bf16x8*)(&sH1[idx]);
        a3 = MFMA(w3, bh, a3);
        a3 = MFMA(w3, bl, a3);
      }
      f32x4 o;
#pragma unroll
      for (int r = 0; r < 4; ++r)
        o[r] = fminf(fmaxf(-a3[r], -1.f), 1.f);
      *(float4*)(&out[((size_t)tile * BM + 16 * wave + l) * CDIM + 4 * q]) = *(float4*)&o;
    } else if (it + 1 < ITERS) {
      // ---- waves 4-7: stage next X tile concurrently with layer 3 ----
      const float* xp = x + (size_t)(tile + GRID) * BM * SDIM;
      const int tid2 = tid - 256;
#pragma unroll
      for (int i = 0; i < 4; ++i) {
        const int e = i * 256 + tid2;        // 1024 float4 = 64 x 64 floats
        const int r = e >> 4, k4 = (e & 15) * 4;
        const float4 v = *(const float4*)(xp + r * SDIM + k4);
        bf16x4 w = {(bf16)v.x, (bf16)v.y, (bf16)v.z, (bf16)v.w};
        *(bf16x4*)(&sX[r * LDX + k4]) = w;
      }
    }
    __syncthreads();   // D: L3 reads + stage done before next L1 overwrites sH1/reads sX
  }
}

extern "C" void kernel_launch(void* const* d_in, const int* in_sizes, int n_in,
                              void* d_out, int out_size, void* d_ws, size_t ws_size,
                              hipStream_t stream) {
  const float* x    = (const float*)d_in[0];
  const float* t    = (const float*)d_in[1];
  const float* W1   = (const float*)d_in[2];
  const float* b1   = (const float*)d_in[3];
  const float* W2   = (const float*)d_in[4];
  const float* b2   = (const float*)d_in[5];
  const float* W3   = (const float*)d_in[6];
  const float* b3   = (const float*)d_in[7];
  const float* Bmat = (const float*)d_in[8];
  float* out = (float*)d_out;
  bf16*  w3ws = (bf16*)d_ws;

  hipLaunchKernelGGL(oc_main, dim3(GRID), dim3(512), 0, stream,
                     x, t, W1, b1, W2, b2, W3, b3, Bmat, w3ws, out);
}

// Round 8
// 126.374 us; speedup vs baseline: 1.8000x; 1.7481x over previous
//
#include <hip/hip_runtime.h>

// ImplicitNetOC: u = clip(-pB) ; pB = relu(relu([x,t]W1+b1)W2+b2) @ (W3@Bmat) + b3@Bmat
// R8: BM=64, 2 blocks/CU for real this time. R6/R7 failed because W2-in-registers
// needs ~190 unified regs -> forced spill at the 128-reg budget 4 waves/EU implies.
// Fix: W2 + W3B live in d_ws as pre-packed MFMA A-fragments (pack kernel), streamed
// by coalesced dwordx4 loads in the K-loop (L2-resident, compiler-pipelined).
// Per-thread state drops to ~105 unified regs -> no spill at 4 waves/EU.

typedef __bf16 bf16;
typedef __bf16 bf16x8 __attribute__((ext_vector_type(8)));
typedef __bf16 bf16x4 __attribute__((ext_vector_type(4)));
typedef float  f32x4  __attribute__((ext_vector_type(4)));

#define HID    256
#define SDIM   64
#define CDIM   16
#define BM     64
#define GRID   512      // 2 blocks per CU
#define ITERS  4        // 131072 / (BM*GRID)
#define LDH    264      // bf16 stride (528 B = 132 dw == 4 mod 32 banks: balanced)
#define LDX    72       // bf16 stride (144 B = 36 dw == 4 mod 32 banks: balanced)

// ws byte offsets
#define OFF_W2P 0        // 8192 frag-entries x 16 B = 131072 (8kt x 16nt x 64lane)
#define OFF_W3P 131072   // 512 entries x 16 B = 8192   (8kt x 64lane)
#define OFF_B1E 139264   // 256 f32
#define OFF_B3B 140288   // 16 f32

#define MFMA(a, b, c) __builtin_amdgcn_mfma_f32_16x16x32_bf16(a, b, c, 0, 0, 0)

__device__ __forceinline__ int sh_idx(int row, int h) { return row * LDH + h; }

// ---- pack kernel: W2 A-frags, W3B A-frags, folded biases -> ws. 18 x 512 ----
__global__ __launch_bounds__(512)
void oc_pack(const float* __restrict__ t,  const float* __restrict__ W1,
             const float* __restrict__ b1, const float* __restrict__ W2,
             const float* __restrict__ W3, const float* __restrict__ b3,
             const float* __restrict__ Bmat, char* __restrict__ ws) {
  const int gid = blockIdx.x * 512 + threadIdx.x;
  if (gid < 8192) {
    // W2^T A-frag entry: lane=gid&63, tt=gid>>6 -> nt=tt&15, kt=tt>>4
    // A[m][k]: m = nt*16 + (lane&15) (hidden-out), k = kt*32 + (lane>>4)*8 + j (hidden-in)
    const int lane = gid & 63, tt = gid >> 6;
    const int nt = tt & 15, kt = tt >> 4;
    const int m = nt * 16 + (lane & 15);
    const int k0 = kt * 32 + ((lane >> 4) << 3);
    bf16x8 v;
#pragma unroll
    for (int j = 0; j < 8; ++j) v[j] = (bf16)W2[(k0 + j) * HID + m];
    *(bf16x8*)((bf16*)(ws + OFF_W2P) + (size_t)gid * 8) = v;
  } else if (gid < 8704) {
    // W3B^T A-frag entry: e=gid-8192: kt=e>>6, fl=e&63
    const int e = gid - 8192, kt = e >> 6, fl = e & 63;
    const int r0 = kt * 32 + ((fl >> 4) << 3);   // hidden rows r0..r0+7
    const int c  = fl & 15;                      // control col
    float aw[8];
#pragma unroll
    for (int j = 0; j < 8; ++j) aw[j] = 0.f;
    for (int m = 0; m < SDIM; ++m) {
      const float bm = Bmat[m * CDIM + c];
#pragma unroll
      for (int j = 0; j < 8; ++j) aw[j] = fmaf(W3[(r0 + j) * SDIM + m], bm, aw[j]);
    }
    bf16x8 v;
#pragma unroll
    for (int j = 0; j < 8; ++j) v[j] = (bf16)aw[j];
    *(bf16x8*)((bf16*)(ws + OFF_W3P) + (size_t)e * 8) = v;
  } else if (gid < 8960) {
    const int h = gid - 8704;
    ((float*)(ws + OFF_B1E))[h] = b1[h] + t[0] * W1[SDIM * HID + h];  // fold t-col
  } else if (gid < 8976) {
    const int c = gid - 8960;
    float s = 0.f;
    for (int m = 0; m < SDIM; ++m) s = fmaf(b3[m], Bmat[m * CDIM + c], s);
    ((float*)(ws + OFF_B3B))[c] = s;
  }
}

// ---- main: 512 blocks x 512 threads, 76.8 KB LDS -> 2 blocks/CU ----
__global__ __launch_bounds__(512, 2)
void oc_main(const float* __restrict__ x,  const float* __restrict__ W1,
             const float* __restrict__ b2, const char* __restrict__ ws,
             float* __restrict__ out) {
  __shared__ bf16 sH1[BM * LDH];   // H1 [batch][hidden]; reused as H2-lo
  __shared__ bf16 sH2[BM * LDH];   // H2-hi
  __shared__ bf16 sX [BM * LDX];   // staged X [batch][k]
  const int tid  = threadIdx.x;
  const int wave = tid >> 6, lane = tid & 63;
  const int q    = lane >> 4, l = lane & 15;

  const bf16* W2p = (const bf16*)(ws + OFF_W2P);
  const bf16* W3p = (const bf16*)(ws + OFF_W3P);

  // ---- initial X stage ----
  {
    const float* xp = x + (size_t)blockIdx.x * BM * SDIM;
#pragma unroll
    for (int i = 0; i < 2; ++i) {
      const int e = i * 512 + tid;           // 1024 float4 = 64 x 64 floats
      const int r = e >> 4, k4 = (e & 15) * 4;
      const float4 v = *(const float4*)(xp + r * SDIM + k4);
      bf16x4 w = {(bf16)v.x, (bf16)v.y, (bf16)v.z, (bf16)v.w};
      *(bf16x4*)(&sX[r * LDX + k4]) = w;
    }
  }

  // ---- W1^T A-frags in registers (16 VGPRs) + biases (float4 from ws/b2) ----
  bf16x8 W1t[2][2];
#pragma unroll
  for (int kt = 0; kt < 2; ++kt)
#pragma unroll
    for (int mt = 0; mt < 2; ++mt) {
      bf16x8 v;
#pragma unroll
      for (int j = 0; j < 8; ++j)
        v[j] = (bf16)W1[(32 * kt + 8 * q + j) * HID + 32 * wave + 16 * mt + l];
      W1t[kt][mt] = v;
    }
  f32x4 b1e[2], b2e[2];
#pragma unroll
  for (int mt = 0; mt < 2; ++mt) {
    const int h0 = 32 * wave + 16 * mt + 4 * q;
    const float4 v1 = *(const float4*)((const float*)(ws + OFF_B1E) + h0);
    const float4 v2 = *(const float4*)(b2 + h0);
    b1e[mt] = (f32x4){v1.x, v1.y, v1.z, v1.w};
    b2e[mt] = (f32x4){v2.x, v2.y, v2.z, v2.w};
  }
  f32x4 b3t;
  {
    const float4 v = *(const float4*)((const float*)(ws + OFF_B3B) + 4 * q);
    b3t = (f32x4){v.x, v.y, v.z, v.w};
  }
  __syncthreads();   // sX staged

  f32x4 acc[2][4];

  for (int it = 0; it < ITERS; ++it) {
    const int tile = blockIdx.x + it * GRID;

    // ---- layer 1: H1 = relu(W1^T X^T + b1)  M=32 hidden/wave, N=64 batch ----
#pragma unroll
    for (int mt = 0; mt < 2; ++mt)
#pragma unroll
      for (int nt = 0; nt < 4; ++nt) acc[mt][nt] = b1e[mt];
#pragma unroll
    for (int kt = 0; kt < 2; ++kt)
#pragma unroll
      for (int nt = 0; nt < 4; ++nt) {
        const bf16x8 b = *(const bf16x8*)(&sX[(16 * nt + l) * LDX + 32 * kt + 8 * q]);
        acc[0][nt] = MFMA(W1t[kt][0], b, acc[0][nt]);
        acc[1][nt] = MFMA(W1t[kt][1], b, acc[1][nt]);
      }
#pragma unroll
    for (int mt = 0; mt < 2; ++mt) {
      const int h0 = 32 * wave + 16 * mt + 4 * q;
#pragma unroll
      for (int nt = 0; nt < 4; ++nt) {
        bf16x4 v;
#pragma unroll
        for (int r = 0; r < 4; ++r) v[r] = (bf16)fmaxf(acc[mt][nt][r], 0.f);
        *(bf16x4*)(&sH1[sh_idx(16 * nt + l, h0)]) = v;
      }
    }
    __syncthreads();   // A: H1 visible; sX reads done

    // ---- layer 2: H2 = relu(W2^T H1 + b2)  K=256; W2 frags streamed from ws ----
#pragma unroll
    for (int mt = 0; mt < 2; ++mt)
#pragma unroll
      for (int nt = 0; nt < 4; ++nt) acc[mt][nt] = b2e[mt];
#pragma unroll
    for (int kt = 0; kt < 8; ++kt) {
      const bf16x8 w2a = *(const bf16x8*)(W2p + ((size_t)(kt * 16 + 2 * wave    ) * 64 + lane) * 8);
      const bf16x8 w2b = *(const bf16x8*)(W2p + ((size_t)(kt * 16 + 2 * wave + 1) * 64 + lane) * 8);
#pragma unroll
      for (int nt = 0; nt < 4; ++nt) {
        const bf16x8 b = *(const bf16x8*)(&sH1[sh_idx(16 * nt + l, 32 * kt + 8 * q)]);
        acc[0][nt] = MFMA(w2a, b, acc[0][nt]);
        acc[1][nt] = MFMA(w2b, b, acc[1][nt]);
      }
    }
    __syncthreads();   // B: sH1 reads done -> overwritable as H2-lo

    // ---- H2 writeback: hi (sH2) + lo residual (sH1), b64 each ----
#pragma unroll
    for (int mt = 0; mt < 2; ++mt) {
      const int h0 = 32 * wave + 16 * mt + 4 * q;
#pragma unroll
      for (int nt = 0; nt < 4; ++nt) {
        bf16x4 hi, lo;
#pragma unroll
        for (int r = 0; r < 4; ++r) {
          const float v = fmaxf(acc[mt][nt][r], 0.f);
          const bf16 h = (bf16)v;
          hi[r] = h;
          lo[r] = (bf16)(v - (float)h);
        }
        const int idx = sh_idx(16 * nt + l, h0);
        *(bf16x4*)(&sH2[idx]) = hi;
        *(bf16x4*)(&sH1[idx]) = lo;
      }
    }
    __syncthreads();   // C: H2 hi/lo visible

    if (wave < 4) {
      // ---- layer 3 (waves 0-3): u = clip(-(W3B^T(H2hi+H2lo) + b3B)), 16 rows/wave ----
      f32x4 a3 = b3t;
#pragma unroll
      for (int kt = 0; kt < 8; ++kt) {
        const bf16x8 w3 = *(const bf16x8*)(W3p + ((size_t)kt * 64 + lane) * 8);
        const int idx = sh_idx(16 * wave + l, 32 * kt + 8 * q);
        const bf16x8 bh = *(const bf16x8*)(&sH2[idx]);
        const bf16x8 bl = *(const bf16x8*)(&sH1[idx]);
        a3 = MFMA(w3, bh, a3);
        a3 = MFMA(w3, bl, a3);
      }
      f32x4 o;
#pragma unroll
      for (int r = 0; r < 4; ++r)
        o[r] = fminf(fmaxf(-a3[r], -1.f), 1.f);
      *(float4*)(&out[((size_t)tile * BM + 16 * wave + l) * CDIM + 4 * q]) = *(float4*)&o;
    } else if (it + 1 < ITERS) {
      // ---- waves 4-7: stage next X tile concurrently with layer 3 ----
      const float* xp = x + (size_t)(tile + GRID) * BM * SDIM;
      const int tid2 = tid - 256;
#pragma unroll
      for (int i = 0; i < 4; ++i) {
        const int e = i * 256 + tid2;        // 1024 float4 = 64 x 64 floats
        const int r = e >> 4, k4 = (e & 15) * 4;
        const float4 v = *(const float4*)(xp + r * SDIM + k4);
        bf16x4 w = {(bf16)v.x, (bf16)v.y, (bf16)v.z, (bf16)v.w};
        *(bf16x4*)(&sX[r * LDX + k4]) = w;
      }
    }
    __syncthreads();   // D: L3 reads + stage done before next L1 overwrites sH1/reads sX
  }
}

extern "C" void kernel_launch(void* const* d_in, const int* in_sizes, int n_in,
                              void* d_out, int out_size, void* d_ws, size_t ws_size,
                              hipStream_t stream) {
  const float* x    = (const float*)d_in[0];
  const float* t    = (const float*)d_in[1];
  const float* W1   = (const float*)d_in[2];
  const float* b1   = (const float*)d_in[3];
  const float* W2   = (const float*)d_in[4];
  const float* b2   = (const float*)d_in[5];
  const float* W3   = (const float*)d_in[6];
  const float* b3   = (const float*)d_in[7];
  const float* Bmat = (const float*)d_in[8];
  float* out = (float*)d_out;
  char*  ws  = (char*)d_ws;

  hipLaunchKernelGGL(oc_pack, dim3(18), dim3(512), 0, stream,
                     t, W1, b1, W2, W3, b3, Bmat, ws);
  hipLaunchKernelGGL(oc_main, dim3(GRID), dim3(512), 0, stream,
                     x, W1, b2, ws, out);
}